// Round 15
// baseline (111.949 us; speedup 1.0000x reference)
//
#include <hip/hip_runtime.h>

#define NN 128
#define CCH 16
#define BB 4
#define HID 128
#define DOUT 128

// ---------------------------------------------------------------------------
// Single fused kernel. Block = (b, row p), 1024 threads = 16 waves, 2 blk/CU,
// 8192 waves = full machine. XCD swizzle keeps each XCD's strided working set
// inside its 4 MiB L2 (R14 counters: FETCH 3.66 MB ~= input size).
//
// Phase 1 (hot loop): PURE SCALAR, 13 VALU per k per q-pair. Weights are
// wave-uniform s_loads consumed directly as SGPR operands in v_fma_f32
// (1 SGPR/instr — legal); NO v2f, NO splat v_movs (R13's ~20 inst/k -> 13).
// a = w.x*xpp + b1k shared across the q-pair.
// Diag: mask q==p, 64-lane shuffle reduce per wave (wave = channel c).
// Phase 2: wave wv -> 8 d's (scalar Wc/bc), lane = m-pair, scalar fma.
// ---------------------------------------------------------------------------
__global__ __launch_bounds__(1024, 8) void fused_rey(
    const float* __restrict__ x,
    const float* __restrict__ W1, const float* __restrict__ b1,
    const float* __restrict__ W2, const float* __restrict__ b2,
    const float* __restrict__ Wc, const float* __restrict__ bc,
    float* __restrict__ y)
{
    __shared__ float s_out[CCH][NN];   // 8 KB
    __shared__ float s_diag[CCH];

    const int t    = threadIdx.x;
    const int bid0 = blockIdx.x;
    const int bid  = ((bid0 & 7) << 6) | (bid0 >> 3);   // XCD-contiguous (bijective)
    const int p    = bid & 127;
    const int b    = bid >> 7;
    const int c    = t >> 6;           // 0..15, wave-uniform
    const int lane = t & 63;
    const int q0   = lane * 2;         // q pair {q0, q0+1}

    const float* xm = x + (((size_t)(b * CCH + c)) << 14);

    // per-thread x loads (strided ones hit per-XCD L2 thanks to the swizzle)
    const float2 vpq = *reinterpret_cast<const float2*>(&xm[p * NN + q0]);  // coalesced
    const float xpq0 = vpq.x,              xpq1 = vpq.y;
    const float xqp0 = xm[q0 * NN + p],    xqp1 = xm[(q0 + 1) * NN + p];
    const float xqq0 = xm[q0 * (NN + 1)],  xqq1 = xm[(q0 + 1) * (NN + 1)];
    const float xpp  = xm[p * (NN + 1)];   // wave-uniform -> scalar load

    const float bb0 = b2[0], bb1 = b2[1];
    float h0a = 0.f, h0b = 0.f, h1a = 0.f, h1b = 0.f;

    // ---- phase 1: hidden loop, scalar, SGPR weight operands ----
    #pragma unroll 4
    for (int k = 0; k < HID; ++k) {
        const float4 w  = reinterpret_cast<const float4*>(W1)[k];  // s_load_dwordx4
        const float b1k = b1[k];
        const float w20 = W2[k];
        const float w21 = W2[HID + k];
        const float a = fmaf(w.x, xpp, b1k);      // q-invariant, shared
        float u = fmaf(w.y, xpq0, a);
        u = fmaf(w.z, xqp0, u);
        u = fmaf(w.w, xqq0, u);
        u = fmaxf(u, 0.f);
        h0a = fmaf(w20, u, h0a);
        h1a = fmaf(w21, u, h1a);
        float v = fmaf(w.y, xpq1, a);
        v = fmaf(w.z, xqp1, v);
        v = fmaf(w.w, xqq1, v);
        v = fmaxf(v, 0.f);
        h0b = fmaf(w20, v, h0b);
        h1b = fmaf(w21, v, h1b);
    }

    // off-diagonal h1 (+b2[1]) -> LDS row c; (c,p) slot fixed after barrier
    s_out[c][q0]     = h1a + bb1;
    s_out[c][q0 + 1] = h1b + bb1;

    // diag partial: mask q==p, 64-lane wave reduce
    float s = ((q0 == p) ? 0.f : h0a) + ((q0 + 1 == p) ? 0.f : h0b);
    #pragma unroll
    for (int off = 32; off > 0; off >>= 1)
        s += __shfl_down(s, off, 64);
    if (lane == 0) s_diag[c] = s * (1.0f / (NN - 1)) + bb0;

    __syncthreads();
    if (t < CCH) s_out[t][p] = s_diag[t];
    __syncthreads();

    // ---- phase 2: y[b,d,p,:] = relu(sum_c s_out[c]*Wc[d][c] + bc[d]) ----
    const int wv = t >> 6;             // 0..15 -> 8 d's each (wave-uniform)
    const int m0 = lane * 2;
    float rx[CCH], ry[CCH];
    #pragma unroll
    for (int cc = 0; cc < CCH; ++cc) {
        const float2 rv = *reinterpret_cast<const float2*>(&s_out[cc][m0]);
        rx[cc] = rv.x; ry[cc] = rv.y;
    }

    #pragma unroll 2
    for (int dd = 0; dd < 8; ++dd) {
        const int d = wv * 8 + dd;         // wave-uniform
        const float bcv = bc[d];           // scalar load
        float ax = bcv, ay = bcv;
        #pragma unroll
        for (int cc = 0; cc < CCH; ++cc) {
            const float wcf = Wc[d * CCH + cc];   // scalar load, SGPR operand
            ax = fmaf(wcf, rx[cc], ax);
            ay = fmaf(wcf, ry[cc], ay);
        }
        float2 ov;
        ov.x = fmaxf(ax, 0.f);
        ov.y = fmaxf(ay, 0.f);
        *reinterpret_cast<float2*>(
            &y[(((size_t)(b * DOUT + d)) * NN + p) * NN + m0]) = ov;
    }
}

extern "C" void kernel_launch(void* const* d_in, const int* in_sizes, int n_in,
                              void* d_out, int out_size, void* d_ws, size_t ws_size,
                              hipStream_t stream) {
    const float* x  = (const float*)d_in[0];
    const float* W1 = (const float*)d_in[1];
    const float* b1 = (const float*)d_in[2];
    const float* W2 = (const float*)d_in[3];
    const float* b2 = (const float*)d_in[4];
    const float* Wc = (const float*)d_in[5];
    const float* bc = (const float*)d_in[6];
    float* y = (float*)d_out;

    fused_rey<<<dim3(BB * NN), 1024, 0, stream>>>(x, W1, b1, W2, b2, Wc, bc, y);
}

// Round 16
// 35.945 us; speedup vs baseline: 3.1144x; 3.1144x over previous
//
#include <hip/hip_runtime.h>

#define NN 128
#define CCH 16
#define BB 4
#define HID 128
#define DOUT 128

typedef float v2f __attribute__((ext_vector_type(2)));

// ---------------------------------------------------------------------------
// Single fused kernel. Block = (b, row p), 512 threads = 8 waves, grid 512.
// XCD swizzle kept (bijective). launch_bounds (512,4): VGPR cap 128 -> no
// squeeze-spill (R15 lesson); allocator should land ~48-64 -> 2-4 blk/CU.
//
// Phase 1: thread (c = t>>5, qg = t&31) owns channel c and FOUR q's
//   q0 = qg*4 .. +3, as two v2f pairs. The v2f body shape is kept exactly
//   (R7 probe: s_load weights, no spill, FETCH ~4 MB). Per-k overhead
//   (weight splats, a = w.x*xpp+b1k, bookkeeping) is amortized over 4 cells
//   instead of 2 -> ~4.5 inst/cell vs R13's ~8.5.
// Diag: mask q==p, width-32 shuffle (lanes of one c are one 32-lane group).
// Phase 2: wave wv -> 16 d's (wave-uniform -> scalar Wc/bc), lane = m-pair.
// ---------------------------------------------------------------------------
__global__ __launch_bounds__(512, 4) void fused_rey(
    const float* __restrict__ x,
    const float* __restrict__ W1, const float* __restrict__ b1,
    const float* __restrict__ W2, const float* __restrict__ b2,
    const float* __restrict__ Wc, const float* __restrict__ bc,
    float* __restrict__ y)
{
    __shared__ float s_out[CCH][NN];   // 8 KB
    __shared__ float s_diag[CCH];

    const int t    = threadIdx.x;
    const int bid0 = blockIdx.x;
    const int bid  = ((bid0 & 7) << 6) | (bid0 >> 3);   // XCD-contiguous (bijective)
    const int p    = bid & 127;
    const int b    = bid >> 7;
    const int c    = t >> 5;           // 0..15 (half-wave uniform)
    const int qg   = t & 31;
    const int q0   = qg * 4;           // q quad {q0..q0+3}

    const float* xm = x + (((size_t)(b * CCH + c)) << 14);

    // per-thread x loads (v2f pairs; strided ones served by per-XCD L2)
    const float4 vpq = *reinterpret_cast<const float4*>(&xm[p * NN + q0]);  // coalesced
    const v2f xpq01 = { vpq.x, vpq.y }, xpq23 = { vpq.z, vpq.w };
    const v2f xqp01 = { xm[q0 * NN + p],       xm[(q0 + 1) * NN + p] };
    const v2f xqp23 = { xm[(q0 + 2) * NN + p], xm[(q0 + 3) * NN + p] };
    const v2f xqq01 = { xm[q0 * (NN + 1)],       xm[(q0 + 1) * (NN + 1)] };
    const v2f xqq23 = { xm[(q0 + 2) * (NN + 1)], xm[(q0 + 3) * (NN + 1)] };
    const float xpp = xm[p * (NN + 1)];

    const float bb0 = b2[0], bb1 = b2[1];
    const v2f z2 = { 0.f, 0.f };
    v2f h0a = z2, h0b = z2, h1a = z2, h1b = z2;

    // ---- phase 1: hidden loop (v2f body, 4 cells/thread/k) ----
    #pragma unroll 4
    for (int k = 0; k < HID; ++k) {
        const float4 w  = reinterpret_cast<const float4*>(W1)[k];  // s_load_dwordx4
        const float b1k = b1[k];
        const float w20 = W2[k];
        const float w21 = W2[HID + k];
        const float a = fmaf(w.x, xpp, b1k);       // q-invariant, shared by 4 q's
        const v2f av  = { a, a };
        const v2f wy  = { w.y, w.y }, wz = { w.z, w.z }, ww = { w.w, w.w };
        const v2f w20v = { w20, w20 }, w21v = { w21, w21 };

        v2f hd0 = __builtin_elementwise_fma(wy, xpq01, av);
        hd0 = __builtin_elementwise_fma(wz, xqp01, hd0);
        hd0 = __builtin_elementwise_fma(ww, xqq01, hd0);
        hd0 = __builtin_elementwise_max(hd0, z2);
        h0a = __builtin_elementwise_fma(w20v, hd0, h0a);
        h1a = __builtin_elementwise_fma(w21v, hd0, h1a);

        v2f hd1 = __builtin_elementwise_fma(wy, xpq23, av);
        hd1 = __builtin_elementwise_fma(wz, xqp23, hd1);
        hd1 = __builtin_elementwise_fma(ww, xqq23, hd1);
        hd1 = __builtin_elementwise_max(hd1, z2);
        h0b = __builtin_elementwise_fma(w20v, hd1, h0b);
        h1b = __builtin_elementwise_fma(w21v, hd1, h1b);
    }

    // off-diagonal h1 (+b2[1]) -> LDS row c (16B store); (c,p) fixed after barrier
    float4 o;
    o.x = h1a[0] + bb1; o.y = h1a[1] + bb1;
    o.z = h1b[0] + bb1; o.w = h1b[1] + bb1;
    *reinterpret_cast<float4*>(&s_out[c][q0]) = o;

    // diag partial: mask q==p, reduce across the 32 lanes of this c
    float s = ((q0 == p)     ? 0.f : h0a[0]) + ((q0 + 1 == p) ? 0.f : h0a[1])
            + ((q0 + 2 == p) ? 0.f : h0b[0]) + ((q0 + 3 == p) ? 0.f : h0b[1]);
    #pragma unroll
    for (int off = 16; off > 0; off >>= 1)
        s += __shfl_down(s, off, 32);
    if (qg == 0) s_diag[c] = s * (1.0f / (NN - 1)) + bb0;

    __syncthreads();
    if (t < CCH) s_out[t][p] = s_diag[t];
    __syncthreads();

    // ---- phase 2: y[b,d,p,:] = relu(sum_c s_out[c]*Wc[d][c] + bc[d]) ----
    const int wv   = t >> 6;           // 0..7 -> 16 d's each (wave-uniform)
    const int lane = t & 63;
    const int m0   = lane * 2;
    v2f r[CCH];
    #pragma unroll
    for (int cc = 0; cc < CCH; ++cc)
        r[cc] = *reinterpret_cast<const v2f*>(&s_out[cc][m0]);

    #pragma unroll 4
    for (int dd = 0; dd < 16; ++dd) {
        const int d = wv * 16 + dd;        // wave-uniform
        const float bcv = bc[d];           // scalar load
        v2f acc = { bcv, bcv };
        #pragma unroll
        for (int cc = 0; cc < CCH; ++cc) {
            const float wcf = Wc[d * CCH + cc];   // scalar load
            acc = __builtin_elementwise_fma((v2f){ wcf, wcf }, r[cc], acc);
        }
        acc = __builtin_elementwise_max(acc, z2);
        *reinterpret_cast<v2f*>(
            &y[(((size_t)(b * DOUT + d)) * NN + p) * NN + m0]) = acc;
    }
}

extern "C" void kernel_launch(void* const* d_in, const int* in_sizes, int n_in,
                              void* d_out, int out_size, void* d_ws, size_t ws_size,
                              hipStream_t stream) {
    const float* x  = (const float*)d_in[0];
    const float* W1 = (const float*)d_in[1];
    const float* b1 = (const float*)d_in[2];
    const float* W2 = (const float*)d_in[3];
    const float* b2 = (const float*)d_in[4];
    const float* Wc = (const float*)d_in[5];
    const float* bc = (const float*)d_in[6];
    float* y = (float*)d_out;

    fused_rey<<<dim3(BB * NN), 512, 0, stream>>>(x, W1, b1, W2, b2, Wc, bc, y);
}